// Round 1
// baseline (134.501 us; speedup 1.0000x reference)
//
#include <hip/hip_runtime.h>

typedef __attribute__((ext_vector_type(4))) float f32x4;
typedef __attribute__((ext_vector_type(8))) short bf16x8;

#define IDIM   128
#define HID    64
#define TDEPTH 6
#define MTILE  64
#define NWAVES 6
#define BLOCK  (NWAVES * 64)

__device__ __forceinline__ unsigned short f2bf(float f) {
    unsigned int u = __builtin_bit_cast(unsigned int, f);
    unsigned int r = (u + 0x7FFFu + ((u >> 16) & 1u)) >> 16;  // RNE
    return (unsigned short)r;
}

// One block = 64 rows (MTILE). Wave k (k=0..5) computes chain node (2^k - 1):
// h = relu(x @ W1[node] + b1[node]); p = sigmoid(h . W2[node] + b2[node])
// via mfma_f32_16x16x32_bf16, then a 4-wave leaf fold.
// NOTE: no d_ws usage anywhere — the harness re-poisons the full workspace
// (268 MB fill, ~44-88 us) inside the timed stream when the workspace is used,
// which dominated the previous 107 us measurement.
__global__ __launch_bounds__(BLOCK, 3)
void sdt_kernel(const float* __restrict__ x, const float* __restrict__ W1,
                const float* __restrict__ b1, const float* __restrict__ W2,
                const float* __restrict__ b2, const float* __restrict__ leaf,
                float* __restrict__ out) {
    __shared__ unsigned short xs[MTILE][IDIM + 8];   // +8 pad: 2-way bank alias (free)
    __shared__ float p_lds[TDEPTH][MTILE];
    __shared__ float pp[4][MTILE];

    const int tid    = threadIdx.x;
    const int m_base = blockIdx.x * MTILE;

    // ---- stage X tile: fp32 global -> bf16 LDS (coalesced float4 loads) ----
    const float4* xv = reinterpret_cast<const float4*>(x) + (size_t)m_base * (IDIM / 4);
    for (int f = tid; f < MTILE * (IDIM / 4); f += BLOCK) {
        int row = f >> 5;                 // 32 float4 per row
        int c4  = f & 31;
        float4 v = xv[row * 32 + c4];
        unsigned long long pk =
            (unsigned long long)f2bf(v.x) |
            ((unsigned long long)f2bf(v.y) << 16) |
            ((unsigned long long)f2bf(v.z) << 32) |
            ((unsigned long long)f2bf(v.w) << 48);
        *reinterpret_cast<unsigned long long*>(&xs[row][c4 * 4]) = pk;
    }

    const int wave = tid >> 6;            // 0..5 == depth index k
    const int lane = tid & 63;
    const int node = (1 << wave) - 1;     // chain node: 0,1,3,7,15,31
    const int lcol = lane & 15;
    const int lq   = lane >> 4;

    // ---- W1 B-fragments from global, in-register ----
    // B-frag for mfma_f32_16x16x32_bf16: lane holds B[k=(lane>>4)*8+j][n=lane&15].
    // 6 chain nodes = 98 KB fp32 -> L2-resident; loads issued BEFORE the barrier
    // so their latency hides under the x->LDS staging of the other waves.
    bf16x8 bfrag[4][4];                   // [ks][ct] — all indices compile-time
    {
        const float* wsrc = W1 + (size_t)node * IDIM * HID;
        #pragma unroll
        for (int ks = 0; ks < 4; ks++) {
            int k0 = ks * 32 + lq * 8;
            #pragma unroll
            for (int ct = 0; ct < 4; ct++) {
                int col = ct * 16 + lcol;
                bf16x8 v;
                #pragma unroll
                for (int j = 0; j < 8; j++)
                    v[j] = (short)f2bf(wsrc[(k0 + j) * HID + col]);
                bfrag[ks][ct] = v;
            }
        }
    }

    // hoist epilogue params so their latency hides under the GEMM
    float b1v[4], w2v[4];
    #pragma unroll
    for (int ct = 0; ct < 4; ct++) {
        int col = ct * 16 + lcol;
        b1v[ct] = b1[node * HID + col];
        w2v[ct] = W2[node * HID + col];
    }
    const float bias2 = b2[node];

    __syncthreads();

    f32x4 acc[4][4];
    #pragma unroll
    for (int rt = 0; rt < 4; rt++)
        #pragma unroll
        for (int ct = 0; ct < 4; ct++)
            acc[rt][ct] = (f32x4){0.f, 0.f, 0.f, 0.f};

    // ---- GEMM: 64 rows x 64 cols per wave, K=128 in 4 steps ----
    #pragma unroll
    for (int ks = 0; ks < 4; ks++) {
        bf16x8 afrag[4];
        #pragma unroll
        for (int rt = 0; rt < 4; rt++)
            afrag[rt] = *reinterpret_cast<const bf16x8*>(&xs[rt * 16 + lcol][ks * 32 + lq * 8]);
        #pragma unroll
        for (int rt = 0; rt < 4; rt++)
            #pragma unroll
            for (int ct = 0; ct < 4; ct++)
                acc[rt][ct] = __builtin_amdgcn_mfma_f32_16x16x32_bf16(
                    afrag[rt], bfrag[ks][ct], acc[rt][ct], 0, 0, 0);
    }

    // ---- epilogue: relu, dot W2, sigmoid ----
    // C layout: col = ct*16 + lcol, row = rt*16 + lq*4 + r
    #pragma unroll
    for (int rt = 0; rt < 4; rt++) {
        #pragma unroll
        for (int r = 0; r < 4; r++) {
            float s = 0.f;
            #pragma unroll
            for (int ct = 0; ct < 4; ct++) {
                float v = acc[rt][ct][r] + b1v[ct];
                v = v > 0.f ? v : 0.f;
                s += v * w2v[ct];
            }
            #pragma unroll
            for (int d = 1; d < 16; d <<= 1)
                s += __shfl_xor(s, d, 64);
            float p = 1.f / (1.f + __expf(-(s + bias2)));
            if (lcol == 0)
                p_lds[wave][rt * 16 + lq * 4 + r] = p;
        }
    }
    __syncthreads();

    // ---- fold: out[b] = sum_l leaf[l] * prod_k (bit_k(l) ? p_k : 1-p_k) ----
    // Distributed across 4 waves: chunk = bits 4..5 of leaf index (hoisted
    // factor), inner 16 leaves contracted by a 4-level DP (15 lerps).
    if (tid < 4 * MTILE) {
        int row = tid & (MTILE - 1);
        int ch  = tid >> 6;               // 0..3
        float q0 = p_lds[0][row];
        float q1 = p_lds[1][row];
        float q2 = p_lds[2][row];
        float q3 = p_lds[3][row];
        float p4 = p_lds[4][row];
        float p5 = p_lds[5][row];
        float f4 = (ch & 1) ? p4 : 1.f - p4;
        float f5 = (ch & 2) ? p5 : 1.f - p5;
        const float* lf = leaf + ch * 16;
        float t[8];
        #pragma unroll
        for (int j = 0; j < 8; j++) {
            float a = lf[2 * j], b = lf[2 * j + 1];
            t[j] = a + q0 * (b - a);      // contract bit 0
        }
        #pragma unroll
        for (int j = 0; j < 4; j++) t[j] = t[2 * j] + q1 * (t[2 * j + 1] - t[2 * j]);
        #pragma unroll
        for (int j = 0; j < 2; j++) t[j] = t[2 * j] + q2 * (t[2 * j + 1] - t[2 * j]);
        float s = t[0] + q3 * (t[1] - t[0]);
        pp[ch][row] = f4 * f5 * s;
    }
    __syncthreads();
    if (tid < MTILE)
        out[m_base + tid] = (pp[0][tid] + pp[1][tid]) + (pp[2][tid] + pp[3][tid]);
}

extern "C" void kernel_launch(void* const* d_in, const int* in_sizes, int n_in,
                              void* d_out, int out_size, void* d_ws, size_t ws_size,
                              hipStream_t stream) {
    const float* x    = (const float*)d_in[0];
    const float* W1   = (const float*)d_in[1];
    const float* b1   = (const float*)d_in[2];
    const float* W2   = (const float*)d_in[3];
    const float* b2   = (const float*)d_in[4];
    const float* leaf = (const float*)d_in[5];
    float* out = (float*)d_out;

    const int Bn = in_sizes[0] / IDIM;     // 65536
    const int nblocks = Bn / MTILE;        // 1024

    (void)d_ws; (void)ws_size;             // deliberately unused: avoids timed re-poison fill
    sdt_kernel<<<nblocks, BLOCK, 0, stream>>>(x, W1, b1, W2, b2, leaf, out);
}

// Round 2
// 112.413 us; speedup vs baseline: 1.1965x; 1.1965x over previous
//
#include <hip/hip_runtime.h>

typedef __attribute__((ext_vector_type(4))) float f32x4;
typedef __attribute__((ext_vector_type(8))) short bf16x8;
typedef __attribute__((ext_vector_type(4))) unsigned int u32x4;

#define IDIM   128
#define HID    64
#define TDEPTH 6
#define MTILE  64
#define NWAVES 6
#define BLOCK  (NWAVES * 64)

__device__ __forceinline__ unsigned short f2bf(float f) {
    unsigned int u = __builtin_bit_cast(unsigned int, f);
    unsigned int r = (u + 0x7FFFu + ((u >> 16) & 1u)) >> 16;  // RNE
    return (unsigned short)r;
}

// Pack two fp32 -> one u32 of 2 bf16 (RNE), minimal VALU:
// hi = (u1+rnd1) & 0xFFFF0000 ; lo = (u0+rnd0) >> 16 ; pk = hi | lo
__device__ __forceinline__ unsigned int f2bf_pk(float f0, float f1) {
    unsigned int u0 = __builtin_bit_cast(unsigned int, f0);
    unsigned int u1 = __builtin_bit_cast(unsigned int, f1);
    unsigned int t0 = u0 + 0x7FFFu + ((u0 >> 16) & 1u);
    unsigned int t1 = u1 + 0x7FFFu + ((u1 >> 16) & 1u);
    return (t1 & 0xFFFF0000u) | (t0 >> 16);
}

// One block = 64 rows (MTILE). Wave k (k=0..5) computes chain node (2^k - 1):
// h = relu(x @ W1[node] + b1[node]); p = sigmoid(h . W2[node] + b2[node])
// via mfma_f32_16x16x32_bf16, then a 4-wave leaf fold.
// d_ws is deliberately unused (harness re-poisons the full 268 MB workspace
// inside the timed stream when used — round 0 lesson).
// W1 fragments are built per-ks (live set = 4 frags = 16 VGPR) — building all
// 16 up front spilled to scratch (round 1: VGPR=84, WRITE_SIZE=27MB, 67 us).
__global__ __launch_bounds__(BLOCK, 2)
void sdt_kernel(const float* __restrict__ x, const float* __restrict__ W1,
                const float* __restrict__ b1, const float* __restrict__ W2,
                const float* __restrict__ b2, const float* __restrict__ leaf,
                float* __restrict__ out) {
    __shared__ unsigned short xs[MTILE][IDIM + 8];   // +8 pad: 2-way bank alias (free)
    __shared__ float p_lds[TDEPTH][MTILE];
    __shared__ float pp[4][MTILE];

    const int tid    = threadIdx.x;
    const int m_base = blockIdx.x * MTILE;

    // ---- stage X tile: fp32 global -> bf16 LDS (coalesced float4 loads) ----
    const float4* xv = reinterpret_cast<const float4*>(x) + (size_t)m_base * (IDIM / 4);
    for (int f = tid; f < MTILE * (IDIM / 4); f += BLOCK) {
        int row = f >> 5;                 // 32 float4 per row
        int c4  = f & 31;
        float4 v = xv[row * 32 + c4];
        unsigned long long pk =
            (unsigned long long)f2bf(v.x) |
            ((unsigned long long)f2bf(v.y) << 16) |
            ((unsigned long long)f2bf(v.z) << 32) |
            ((unsigned long long)f2bf(v.w) << 48);
        *reinterpret_cast<unsigned long long*>(&xs[row][c4 * 4]) = pk;
    }

    const int wave = tid >> 6;            // 0..5 == depth index k
    const int lane = tid & 63;
    const int node = (1 << wave) - 1;     // chain node: 0,1,3,7,15,31
    const int lcol = lane & 15;
    const int lq   = lane >> 4;

    // hoist epilogue params so their latency hides under the GEMM
    float b1v[4], w2v[4];
    #pragma unroll
    for (int ct = 0; ct < 4; ct++) {
        int col = ct * 16 + lcol;
        b1v[ct] = b1[node * HID + col];
        w2v[ct] = W2[node * HID + col];
    }
    const float bias2 = b2[node];

    __syncthreads();

    f32x4 acc[4][4];
    #pragma unroll
    for (int rt = 0; rt < 4; rt++)
        #pragma unroll
        for (int ct = 0; ct < 4; ct++)
            acc[rt][ct] = (f32x4){0.f, 0.f, 0.f, 0.f};

    // ---- GEMM: 64 rows x 64 cols per wave, K=128 in 4 steps ----
    // B-frag for mfma_f32_16x16x32_bf16: lane holds B[k=(lane>>4)*8+j][n=lane&15].
    // 6 chain nodes of W1 = 192 KB fp32 -> L2-resident after first touch; the
    // 32 scalar loads per ks pipeline under the previous step's 16 MFMAs.
    const float* wsrc = W1 + (size_t)node * IDIM * HID + lcol;
    #pragma unroll
    for (int ks = 0; ks < 4; ks++) {
        const int k0 = ks * 32 + lq * 8;
        bf16x8 bfrag[4];
        #pragma unroll
        for (int ct = 0; ct < 4; ct++) {
            const float* wc = wsrc + (size_t)k0 * HID + ct * 16;
            u32x4 pk;
            #pragma unroll
            for (int jp = 0; jp < 4; jp++)
                pk[jp] = f2bf_pk(wc[(2 * jp) * HID], wc[(2 * jp + 1) * HID]);
            bfrag[ct] = __builtin_bit_cast(bf16x8, pk);
        }
        bf16x8 afrag[4];
        #pragma unroll
        for (int rt = 0; rt < 4; rt++)
            afrag[rt] = *reinterpret_cast<const bf16x8*>(&xs[rt * 16 + lcol][ks * 32 + lq * 8]);
        #pragma unroll
        for (int rt = 0; rt < 4; rt++)
            #pragma unroll
            for (int ct = 0; ct < 4; ct++)
                acc[rt][ct] = __builtin_amdgcn_mfma_f32_16x16x32_bf16(
                    afrag[rt], bfrag[ct], acc[rt][ct], 0, 0, 0);
    }

    // ---- epilogue: relu, dot W2, sigmoid ----
    // C layout: col = ct*16 + lcol, row = rt*16 + lq*4 + r
    #pragma unroll
    for (int rt = 0; rt < 4; rt++) {
        #pragma unroll
        for (int r = 0; r < 4; r++) {
            float s = 0.f;
            #pragma unroll
            for (int ct = 0; ct < 4; ct++) {
                float v = acc[rt][ct][r] + b1v[ct];
                v = v > 0.f ? v : 0.f;
                s += v * w2v[ct];
            }
            #pragma unroll
            for (int d = 1; d < 16; d <<= 1)
                s += __shfl_xor(s, d, 64);
            float p = 1.f / (1.f + __expf(-(s + bias2)));
            if (lcol == 0)
                p_lds[wave][rt * 16 + lq * 4 + r] = p;
        }
    }
    __syncthreads();

    // ---- fold: out[b] = sum_l leaf[l] * prod_k (bit_k(l) ? p_k : 1-p_k) ----
    // Distributed across 4 waves: chunk = bits 4..5 of leaf index (hoisted
    // factor), inner 16 leaves contracted by a 4-level DP (15 lerps).
    if (tid < 4 * MTILE) {
        int row = tid & (MTILE - 1);
        int ch  = tid >> 6;               // 0..3
        float q0 = p_lds[0][row];
        float q1 = p_lds[1][row];
        float q2 = p_lds[2][row];
        float q3 = p_lds[3][row];
        float p4 = p_lds[4][row];
        float p5 = p_lds[5][row];
        float f4 = (ch & 1) ? p4 : 1.f - p4;
        float f5 = (ch & 2) ? p5 : 1.f - p5;
        const float* lf = leaf + ch * 16;
        float t[8];
        #pragma unroll
        for (int j = 0; j < 8; j++) {
            float a = lf[2 * j], b = lf[2 * j + 1];
            t[j] = a + q0 * (b - a);      // contract bit 0
        }
        #pragma unroll
        for (int j = 0; j < 4; j++) t[j] = t[2 * j] + q1 * (t[2 * j + 1] - t[2 * j]);
        #pragma unroll
        for (int j = 0; j < 2; j++) t[j] = t[2 * j] + q2 * (t[2 * j + 1] - t[2 * j]);
        float s = t[0] + q3 * (t[1] - t[0]);
        pp[ch][row] = f4 * f5 * s;
    }
    __syncthreads();
    if (tid < MTILE)
        out[m_base + tid] = (pp[0][tid] + pp[1][tid]) + (pp[2][tid] + pp[3][tid]);
}

extern "C" void kernel_launch(void* const* d_in, const int* in_sizes, int n_in,
                              void* d_out, int out_size, void* d_ws, size_t ws_size,
                              hipStream_t stream) {
    const float* x    = (const float*)d_in[0];
    const float* W1   = (const float*)d_in[1];
    const float* b1   = (const float*)d_in[2];
    const float* W2   = (const float*)d_in[3];
    const float* b2   = (const float*)d_in[4];
    const float* leaf = (const float*)d_in[5];
    float* out = (float*)d_out;

    const int Bn = in_sizes[0] / IDIM;     // 65536
    const int nblocks = Bn / MTILE;        // 1024

    (void)d_ws; (void)ws_size;             // deliberately unused: avoids timed re-poison fill
    sdt_kernel<<<nblocks, BLOCK, 0, stream>>>(x, W1, b1, W2, b2, leaf, out);
}

// Round 3
// 100.823 us; speedup vs baseline: 1.3340x; 1.1150x over previous
//
#include <hip/hip_runtime.h>

typedef __attribute__((ext_vector_type(4))) float f32x4;
typedef __attribute__((ext_vector_type(8))) short bf16x8;
typedef __attribute__((ext_vector_type(4))) unsigned int u32x4;

#define IDIM    128
#define HID     64
#define TDEPTH  6
#define MTILE   64
#define NWAVES  6
#define BLOCK   (NWAVES * 64)
#define T_TILES 4            // row-tiles per block; W1 fragment cost amortized 4x

__device__ __forceinline__ unsigned short f2bf(float f) {
    unsigned int u = __builtin_bit_cast(unsigned int, f);
    unsigned int r = (u + 0x7FFFu + ((u >> 16) & 1u)) >> 16;  // RNE
    return (unsigned short)r;
}

// Pack two fp32 -> one u32 of 2 bf16 (RNE)
__device__ __forceinline__ unsigned int f2bf_pk(float f0, float f1) {
    unsigned int u0 = __builtin_bit_cast(unsigned int, f0);
    unsigned int u1 = __builtin_bit_cast(unsigned int, f1);
    unsigned int t0 = u0 + 0x7FFFu + ((u0 >> 16) & 1u);
    unsigned int t1 = u1 + 0x7FFFu + ((u1 >> 16) & 1u);
    return (t1 & 0xFFFF0000u) | (t0 >> 16);
}

// Wave k (k=0..5) owns chain node (2^k - 1). Per block: T_TILES tiles of 64 rows.
// W1 B-fragments built ONCE per block, resident in VGPRs (round-2 lesson: per-block
// rebuild was 1024x-redundant VALU+L2 work). X staging double-buffered + pipelined:
// tile t+1 global loads issued before tile t's GEMM (T14 split).
// d_ws deliberately unused (harness re-poisons 268 MB workspace in the timed stream).
__global__ __launch_bounds__(BLOCK, 2)
void sdt_kernel(const float* __restrict__ x, const float* __restrict__ W1,
                const float* __restrict__ b1, const float* __restrict__ W2,
                const float* __restrict__ b2, const float* __restrict__ leaf,
                float* __restrict__ out) {
    __shared__ unsigned short xs[2][MTILE][IDIM + 8];  // double buffer; +8 pad
    __shared__ float p_lds[TDEPTH][MTILE];
    __shared__ float pp[4][MTILE];

    const int tid   = threadIdx.x;
    const int tile0 = blockIdx.x * T_TILES;            // global 64-row tile index

    const int wave = tid >> 6;
    const int lane = tid & 63;
    const int node = (1 << wave) - 1;                  // 0,1,3,7,15,31
    const int lcol = lane & 15;
    const int lq   = lane >> 4;

    const float4* xv = reinterpret_cast<const float4*>(x);

    // ---- issue tile-0 stage loads FIRST (in flight under the W1 build) ----
    float4 sreg[6];
    {
        const float4* xt = xv + (size_t)tile0 * (MTILE * IDIM / 4);
        #pragma unroll
        for (int i = 0; i < 5; i++) sreg[i] = xt[tid + i * BLOCK];
        if (tid < 128) sreg[5] = xt[5 * BLOCK + tid];
    }

    // ---- build W1 B-fragments once (resident for all T_TILES) ----
    // B-frag: lane holds B[k = ks*32 + lq*8 + j][n = ct*16 + lcol]
    bf16x8 bfrag[4][4];
    {
        const float* wsrc = W1 + (size_t)node * IDIM * HID + lcol;
        #pragma unroll
        for (int ks = 0; ks < 4; ks++) {
            const int k0 = ks * 32 + lq * 8;
            #pragma unroll
            for (int ct = 0; ct < 4; ct++) {
                const float* wc = wsrc + (size_t)k0 * HID + ct * 16;
                u32x4 pk;
                #pragma unroll
                for (int jp = 0; jp < 4; jp++)
                    pk[jp] = f2bf_pk(wc[(2 * jp) * HID], wc[(2 * jp + 1) * HID]);
                bfrag[ks][ct] = __builtin_bit_cast(bf16x8, pk);
            }
        }
    }

    // epilogue params (latency hidden under the above)
    float b1v[4], w2v[4];
    #pragma unroll
    for (int ct = 0; ct < 4; ct++) {
        int col = ct * 16 + lcol;
        b1v[ct] = b1[node * HID + col];
        w2v[ct] = W2[node * HID + col];
    }
    const float bias2 = b2[node];

    // ---- write tile 0 into xs[0] ----
    #pragma unroll
    for (int i = 0; i < 5; i++) {
        int f = tid + i * BLOCK, row = f >> 5, c4 = f & 31;
        float4 v = sreg[i];
        unsigned long long pk =
            (unsigned long long)f2bf(v.x) |
            ((unsigned long long)f2bf(v.y) << 16) |
            ((unsigned long long)f2bf(v.z) << 32) |
            ((unsigned long long)f2bf(v.w) << 48);
        *reinterpret_cast<unsigned long long*>(&xs[0][row][c4 * 4]) = pk;
    }
    if (tid < 128) {
        int f = 5 * BLOCK + tid, row = f >> 5, c4 = f & 31;
        float4 v = sreg[5];
        unsigned long long pk =
            (unsigned long long)f2bf(v.x) |
            ((unsigned long long)f2bf(v.y) << 16) |
            ((unsigned long long)f2bf(v.z) << 32) |
            ((unsigned long long)f2bf(v.w) << 48);
        *reinterpret_cast<unsigned long long*>(&xs[0][row][c4 * 4]) = pk;
    }
    __syncthreads();

    int cur = 0;
    for (int t = 0; t < T_TILES; ++t) {
        const bool pf = (t + 1 < T_TILES);
        // ---- prefetch tile t+1 (loads in flight across the GEMM) ----
        if (pf) {
            const float4* xt = xv + (size_t)(tile0 + t + 1) * (MTILE * IDIM / 4);
            #pragma unroll
            for (int i = 0; i < 5; i++) sreg[i] = xt[tid + i * BLOCK];
            if (tid < 128) sreg[5] = xt[5 * BLOCK + tid];
        }

        // ---- GEMM: 64x64 per wave, K=128, bfrag resident ----
        f32x4 acc[4][4];
        #pragma unroll
        for (int rt = 0; rt < 4; rt++)
            #pragma unroll
            for (int ct = 0; ct < 4; ct++)
                acc[rt][ct] = (f32x4){0.f, 0.f, 0.f, 0.f};
        #pragma unroll
        for (int ks = 0; ks < 4; ks++) {
            bf16x8 afrag[4];
            #pragma unroll
            for (int rt = 0; rt < 4; rt++)
                afrag[rt] = *reinterpret_cast<const bf16x8*>(
                    &xs[cur][rt * 16 + lcol][ks * 32 + lq * 8]);
            #pragma unroll
            for (int rt = 0; rt < 4; rt++)
                #pragma unroll
                for (int ct = 0; ct < 4; ct++)
                    acc[rt][ct] = __builtin_amdgcn_mfma_f32_16x16x32_bf16(
                        afrag[rt], bfrag[ks][ct], acc[rt][ct], 0, 0, 0);
        }

        // ---- epilogue: relu, dot W2, sigmoid ----
        #pragma unroll
        for (int rt = 0; rt < 4; rt++) {
            #pragma unroll
            for (int r = 0; r < 4; r++) {
                float s = 0.f;
                #pragma unroll
                for (int ct = 0; ct < 4; ct++) {
                    float v = acc[rt][ct][r] + b1v[ct];
                    v = v > 0.f ? v : 0.f;
                    s += v * w2v[ct];
                }
                #pragma unroll
                for (int d = 1; d < 16; d <<= 1)
                    s += __shfl_xor(s, d, 64);
                float p = 1.f / (1.f + __expf(-(s + bias2)));
                if (lcol == 0)
                    p_lds[wave][rt * 16 + lq * 4 + r] = p;
            }
        }
        __syncthreads();

        // ---- write prefetched tile into the other buffer ----
        if (pf) {
            #pragma unroll
            for (int i = 0; i < 5; i++) {
                int f = tid + i * BLOCK, row = f >> 5, c4 = f & 31;
                float4 v = sreg[i];
                unsigned long long pk =
                    (unsigned long long)f2bf(v.x) |
                    ((unsigned long long)f2bf(v.y) << 16) |
                    ((unsigned long long)f2bf(v.z) << 32) |
                    ((unsigned long long)f2bf(v.w) << 48);
                *reinterpret_cast<unsigned long long*>(&xs[cur ^ 1][row][c4 * 4]) = pk;
            }
            if (tid < 128) {
                int f = 5 * BLOCK + tid, row = f >> 5, c4 = f & 31;
                float4 v = sreg[5];
                unsigned long long pk =
                    (unsigned long long)f2bf(v.x) |
                    ((unsigned long long)f2bf(v.y) << 16) |
                    ((unsigned long long)f2bf(v.z) << 32) |
                    ((unsigned long long)f2bf(v.w) << 48);
                *reinterpret_cast<unsigned long long*>(&xs[cur ^ 1][row][c4 * 4]) = pk;
            }
        }

        // ---- fold (4 waves; concurrent with stage-write threads finishing) ----
        if (tid < 4 * MTILE) {
            int row = tid & (MTILE - 1);
            int ch  = tid >> 6;
            float q0 = p_lds[0][row];
            float q1 = p_lds[1][row];
            float q2 = p_lds[2][row];
            float q3 = p_lds[3][row];
            float p4 = p_lds[4][row];
            float p5 = p_lds[5][row];
            float f4 = (ch & 1) ? p4 : 1.f - p4;
            float f5 = (ch & 2) ? p5 : 1.f - p5;
            const float* lf = leaf + ch * 16;
            float tt[8];
            #pragma unroll
            for (int j = 0; j < 8; j++) {
                float a = lf[2 * j], b = lf[2 * j + 1];
                tt[j] = a + q0 * (b - a);
            }
            #pragma unroll
            for (int j = 0; j < 4; j++) tt[j] = tt[2 * j] + q1 * (tt[2 * j + 1] - tt[2 * j]);
            #pragma unroll
            for (int j = 0; j < 2; j++) tt[j] = tt[2 * j] + q2 * (tt[2 * j + 1] - tt[2 * j]);
            float s = tt[0] + q3 * (tt[1] - tt[0]);
            pp[ch][row] = f4 * f5 * s;
        }
        __syncthreads();
        if (tid < MTILE)
            out[(size_t)(tile0 + t) * MTILE + tid] =
                (pp[0][tid] + pp[1][tid]) + (pp[2][tid] + pp[3][tid]);
        cur ^= 1;
    }
}

extern "C" void kernel_launch(void* const* d_in, const int* in_sizes, int n_in,
                              void* d_out, int out_size, void* d_ws, size_t ws_size,
                              hipStream_t stream) {
    const float* x    = (const float*)d_in[0];
    const float* W1   = (const float*)d_in[1];
    const float* b1   = (const float*)d_in[2];
    const float* W2   = (const float*)d_in[3];
    const float* b2   = (const float*)d_in[4];
    const float* leaf = (const float*)d_in[5];
    float* out = (float*)d_out;

    const int Bn = in_sizes[0] / IDIM;               // 65536
    const int nblocks = Bn / (MTILE * T_TILES);      // 256

    (void)d_ws; (void)ws_size;                       // unused: avoids timed re-poison fill
    sdt_kernel<<<nblocks, BLOCK, 0, stream>>>(x, W1, b1, W2, b2, leaf, out);
}